// Round 10
// baseline (126.438 us; speedup 1.0000x reference)
//
#include <hip/hip_runtime.h>

#define NF4 32   // 128 floats = 32 float4 per (n, channel)
#define NBLK 1024  // grid-stride: 1024 blocks x 8 n/block x 4 iters = 32768

typedef float f4 __attribute__((ext_vector_type(4)));  // clang vector: nontemporal-builtin OK

// ================= compile-time real-CG table =================
// Verified algorithm (R2-R5), evaluated at compile time into a static
// __device__ table; copy_cg moves it to d_ws; tp_main reads it via a
// __restrict__ kernel-arg pointer (the only provenance that preserves the
// fast codegen — R6 literals / R7 laundered pointer spilled, R8 symbol
// lookup aborted the harness).

constexpr double cfact(int n){ double r = 1.0; for (int i = 2; i <= n; ++i) r *= (double)i; return r; }
constexpr int imax2(int a, int b){ return a > b ? a : b; }
constexpr int imin2(int a, int b){ return a < b ? a : b; }
constexpr int iabs_c(int a){ return a < 0 ? -a : a; }
constexpr double csqrt_c(double x){
  double g = x > 1.0 ? x : 1.0;
  for (int i = 0; i < 20; ++i) g = 0.5 * (g + x / g);   // Newton, quadratic -> ulp
  return g;
}

constexpr double cg_cplx_c(int l1,int m1,int l2,int m2,int l3,int m3){
  if (m1 + m2 != m3) return 0.0;
  if (l3 < iabs_c(l1-l2) || l3 > l1+l2) return 0.0;
  double pref = (double)(2*l3+1) * cfact(l1+l2-l3)*cfact(l1-l2+l3)*cfact(-l1+l2+l3)
                / cfact(l1+l2+l3+1);
  pref *= cfact(l3+m3)*cfact(l3-m3)*cfact(l1-m1)*cfact(l1+m1)*cfact(l2-m2)*cfact(l2+m2);
  double s = 0.0;
  int k0 = imax2(0, imax2(l2-l3-m1, l1-l3+m2));
  int k1 = imin2(l1+l2-l3, imin2(l1-m1, l2+m2));
  for (int k = k0; k <= k1; ++k){
    double d = cfact(k)*cfact(l1+l2-l3-k)*cfact(l1-m1-k)*cfact(l2+m2-k)
               *cfact(l3-l2+m1+k)*cfact(l3-l1-m2+k);
    s += ((k & 1) ? -1.0 : 1.0) / d;
  }
  return csqrt_c(pref) * s;
}

struct UC { double re; double im; };
constexpr UC u_ent_c(int l, int i, int m){
  UC u{0.0, 0.0};
  const double s = 0.70710678118654752440;
  int mi = i - l;
  if (mi == 0){ if (m == 0) u.re = 1.0; return u; }
  if (mi > 0){
    if (m == mi)       u.re = ((mi & 1) ? -1.0 : 1.0) * s;
    else if (m == -mi) u.re = s;
    return u;
  }
  int mp = -mi;
  if (m == mi)      u.im = s;                            // column -mp
  else if (m == mp) u.im = -((mp & 1) ? -1.0 : 1.0) * s; // column +mp
  return u;
}

constexpr int deg_c(int A){ return (A==0) ? 0 : (A<4 ? 1 : 2); }

constexpr double real_cg_c(int A, int B, int C){
  int l1 = deg_c(A), i = A - l1*l1;
  int l2 = deg_c(B), j = B - l2*l2;
  int l3 = deg_c(C), k = C - l3*l3;
  if (l3 < iabs_c(l1-l2) || l3 > l1+l2) return 0.0;
  int mi = i - l1, mj = j - l2;
  int alist[2] = {mi, -mi}; int na = (mi == 0) ? 1 : 2;
  int blist[2] = {mj, -mj}; int nb = (mj == 0) ? 1 : 2;
  double tr = 0.0, ti = 0.0;
  for (int ai = 0; ai < na; ++ai){
    for (int bi = 0; bi < nb; ++bi){
      int a = alist[ai], b = blist[bi], c = a + b;
      if (iabs_c(c) > l3) continue;
      UC u3 = u_ent_c(l3, k, c);
      if (u3.re == 0.0 && u3.im == 0.0) continue;
      double cgv = cg_cplx_c(l1, a, l2, b, l3, c);
      if (cgv == 0.0) continue;
      UC u1 = u_ent_c(l1, i, a);
      UC u2 = u_ent_c(l2, j, b);
      double pr = u1.re*u2.re - u1.im*u2.im;
      double pi = u1.re*u2.im + u1.im*u2.re;
      double qr = pr*u3.re + pi*u3.im;   // * conj(u3)
      double qi = pi*u3.re - pr*u3.im;
      tr += qr * cgv; ti += qi * cgv;
    }
  }
  return (((l1+l2+l3) & 1) == 0) ? tr : ti;
}

struct CgTab { float v[729]; };
constexpr CgTab make_cg_tab(){
  CgTab t{};
  for (int A = 0; A < 9; ++A)
    for (int B = 0; B < 9; ++B)
      for (int C = 0; C < 9; ++C)
        t.v[(A*9 + B)*9 + C] = (float)real_cg_c(A, B, C);
  return t;
}
__device__ const CgTab CG_TAB = make_cg_tab();   // static init, lives in .data

// trivial device-side copy: .data symbol -> d_ws (graph-safe, ~2 us)
__global__ void copy_cg(float* __restrict__ ws_f){
  int t = blockIdx.x * blockDim.x + threadIdx.x;
  if (t < 729) ws_f[t] = CG_TAB.v[t];
}

// ================= main tensor-product kernel =================
// R5's proven per-n body, wrapped in a grid-stride loop (4 n per thread,
// #pragma unroll 1 to forbid cross-iteration pipelining -> no VGPR blowup).
// CG values via opaque uniform kernel-arg pointer (scalar loads); all
// x/y/S/acc indices compile-time -> registers; float4 nontemporal streams.

__device__ __forceinline__ void fma4s(f4& s, float v, const f4& a, const f4& b){
  s += v * a * b;
}

template<int l1,int l2,int l3,int r>
__device__ __forceinline__ void do_path(const float* __restrict__ cg,
    const f4* __restrict__ K4, int fi,
    const f4* xv, const f4* yv, f4* acc){
  f4 S[2*l3+1];
  #pragma unroll
  for (int k = 0; k < 2*l3+1; ++k) S[k] = (f4)0.f;
  #pragma unroll
  for (int i = 0; i < 2*l1+1; ++i){
    #pragma unroll
    for (int j = 0; j < 2*l2+1; ++j){
      const int m1 = i - l1, m2 = j - l2;
      const int mu1 = m1 < 0 ? -m1 : m1;
      const int mu2 = m2 < 0 ? -m2 : m2;
      const int s1 = (m1 < 0) ? 1 : 0, s2 = (m2 < 0) ? 1 : 0;
      const int s3 = (((l1+l2+l3) & 1) ? 1 : 0) ^ s1 ^ s2;
      #pragma unroll
      for (int t = 0; t < 2; ++t){
        const int lo  = (mu1 > mu2) ? (mu1 - mu2) : (mu2 - mu1);
        const int mu3 = t ? lo : (mu1 + mu2);
        if (t && lo == mu1 + mu2) continue;   // dedupe when a mu is 0
        if (mu3 > l3) continue;
        if (s3 && mu3 == 0) continue;         // no sin-type m3=0 row
        const int k = (s3 ? -mu3 : mu3) + l3;
        const int A = l1*l1 + i, B = l2*l2 + j, C = l3*l3 + k;
        const float v = cg[A*81 + B*9 + C];
        fma4s(S[k], v, xv[A], yv[B]);
      }
    }
  }
  const int koff = ((l1*3 + l2)*2 + r)*3 + l3;
  const f4 kv = K4[koff*NF4 + fi];
  #pragma unroll
  for (int k = 0; k < 2*l3+1; ++k) acc[k] += kv * S[k];
}

__global__ __launch_bounds__(256) void tp_main(
    const float* __restrict__ xg, const float* __restrict__ yg,
    const float* __restrict__ Kg, float* __restrict__ outg,
    const float* __restrict__ cg){
  const int tid = threadIdx.x;
  const int fi  = tid & 31;            // float4 lane within feature dim
  const int w   = tid >> 5;
  const f4* K4  = (const f4*)Kg;

  #pragma unroll 1
  for (int n = blockIdx.x * 8 + w; n < 32768; n += NBLK * 8){
    const f4* x4 = (const f4*)xg + (size_t)n * 9 * NF4 + fi;
    const f4* y4 = (const f4*)yg + (size_t)n * 9 * NF4 + fi;
    f4* out4 = (f4*)outg + (size_t)n * 18 * NF4 + fi;

    f4 xv[9], yv[9];
    #pragma unroll
    for (int a = 0; a < 9; ++a){
      xv[a] = __builtin_nontemporal_load(&x4[a*NF4]);
      yv[a] = __builtin_nontemporal_load(&y4[a*NF4]);
    }

    f4 acc[5];
    const f4 z4 = (f4)0.f;

    // ---- group (r=0, l3=0): paths (0,0),(1,1),(2,2) -> channel 0
    acc[0] = z4;
    do_path<0,0,0,0>(cg, K4, fi, xv, yv, acc);
    do_path<1,1,0,0>(cg, K4, fi, xv, yv, acc);
    do_path<2,2,0,0>(cg, K4, fi, xv, yv, acc);
    __builtin_nontemporal_store(acc[0], &out4[0*NF4]);

    // ---- group (r=0, l3=1): paths (1,1),(2,2) -> channels 1..3
    #pragma unroll
    for (int k = 0; k < 3; ++k) acc[k] = z4;
    do_path<1,1,1,0>(cg, K4, fi, xv, yv, acc);
    do_path<2,2,1,0>(cg, K4, fi, xv, yv, acc);
    #pragma unroll
    for (int k = 0; k < 3; ++k) __builtin_nontemporal_store(acc[k], &out4[(1+k)*NF4]);

    // ---- group (r=0, l3=2): paths (1,1),(2,2),(0,2),(2,0) -> channels 4..8
    #pragma unroll
    for (int k = 0; k < 5; ++k) acc[k] = z4;
    do_path<1,1,2,0>(cg, K4, fi, xv, yv, acc);
    do_path<2,2,2,0>(cg, K4, fi, xv, yv, acc);
    do_path<0,2,2,0>(cg, K4, fi, xv, yv, acc);
    do_path<2,0,2,0>(cg, K4, fi, xv, yv, acc);
    #pragma unroll
    for (int k = 0; k < 5; ++k) __builtin_nontemporal_store(acc[k], &out4[(4+k)*NF4]);

    // ---- group (r=1, l3=0): no parity-allowed paths -> channel 9 is zero
    __builtin_nontemporal_store(z4, &out4[9*NF4]);

    // ---- group (r=1, l3=1): paths (0,1),(1,0),(1,2),(2,1) -> channels 10..12
    #pragma unroll
    for (int k = 0; k < 3; ++k) acc[k] = z4;
    do_path<0,1,1,1>(cg, K4, fi, xv, yv, acc);
    do_path<1,0,1,1>(cg, K4, fi, xv, yv, acc);
    do_path<1,2,1,1>(cg, K4, fi, xv, yv, acc);
    do_path<2,1,1,1>(cg, K4, fi, xv, yv, acc);
    #pragma unroll
    for (int k = 0; k < 3; ++k) __builtin_nontemporal_store(acc[k], &out4[(10+k)*NF4]);

    // ---- group (r=1, l3=2): paths (1,2),(2,1) -> channels 13..17
    #pragma unroll
    for (int k = 0; k < 5; ++k) acc[k] = z4;
    do_path<1,2,2,1>(cg, K4, fi, xv, yv, acc);
    do_path<2,1,2,1>(cg, K4, fi, xv, yv, acc);
    #pragma unroll
    for (int k = 0; k < 5; ++k) __builtin_nontemporal_store(acc[k], &out4[(13+k)*NF4]);
  }
}

extern "C" void kernel_launch(void* const* d_in, const int* in_sizes, int n_in,
                              void* d_out, int out_size, void* d_ws, size_t ws_size,
                              hipStream_t stream){
  const float* x = (const float*)d_in[0];   // (32768, 1, 9, 128)
  const float* y = (const float*)d_in[1];   // (32768, 1, 9, 128)
  const float* K = (const float*)d_in[2];   // (1,3,1,3,2,3,128)
  float* out = (float*)d_out;               // (32768, 2, 9, 128)
  float* ws_f = (float*)d_ws;

  hipLaunchKernelGGL(copy_cg, dim3(1), dim3(768), 0, stream, ws_f);
  hipLaunchKernelGGL(tp_main, dim3(NBLK), dim3(256), 0, stream,
                     x, y, K, out, ws_f);
}

// Round 11
// 113.115 us; speedup vs baseline: 1.1178x; 1.1178x over previous
//
#include <hip/hip_runtime.h>

#define NF4 32   // 128 floats = 32 float4 per (n, channel)

typedef float f4 __attribute__((ext_vector_type(4)));  // clang vector: nontemporal-builtin OK

// ================= compile-time real-CG table =================
// Verified algorithm (R2-R5), evaluated at compile time into a static
// __device__ table; copy_cg moves it to d_ws; tp_main reads it via a
// __restrict__ kernel-arg pointer (the only provenance that preserves the
// fast codegen — R6 literals / R7 laundered pointer spilled, R8 symbol
// lookup aborted the harness).

constexpr double cfact(int n){ double r = 1.0; for (int i = 2; i <= n; ++i) r *= (double)i; return r; }
constexpr int imax2(int a, int b){ return a > b ? a : b; }
constexpr int imin2(int a, int b){ return a < b ? a : b; }
constexpr int iabs_c(int a){ return a < 0 ? -a : a; }
constexpr double csqrt_c(double x){
  double g = x > 1.0 ? x : 1.0;
  for (int i = 0; i < 20; ++i) g = 0.5 * (g + x / g);   // Newton, quadratic -> ulp
  return g;
}

constexpr double cg_cplx_c(int l1,int m1,int l2,int m2,int l3,int m3){
  if (m1 + m2 != m3) return 0.0;
  if (l3 < iabs_c(l1-l2) || l3 > l1+l2) return 0.0;
  double pref = (double)(2*l3+1) * cfact(l1+l2-l3)*cfact(l1-l2+l3)*cfact(-l1+l2+l3)
                / cfact(l1+l2+l3+1);
  pref *= cfact(l3+m3)*cfact(l3-m3)*cfact(l1-m1)*cfact(l1+m1)*cfact(l2-m2)*cfact(l2+m2);
  double s = 0.0;
  int k0 = imax2(0, imax2(l2-l3-m1, l1-l3+m2));
  int k1 = imin2(l1+l2-l3, imin2(l1-m1, l2+m2));
  for (int k = k0; k <= k1; ++k){
    double d = cfact(k)*cfact(l1+l2-l3-k)*cfact(l1-m1-k)*cfact(l2+m2-k)
               *cfact(l3-l2+m1+k)*cfact(l3-l1-m2+k);
    s += ((k & 1) ? -1.0 : 1.0) / d;
  }
  return csqrt_c(pref) * s;
}

struct UC { double re; double im; };
constexpr UC u_ent_c(int l, int i, int m){
  UC u{0.0, 0.0};
  const double s = 0.70710678118654752440;
  int mi = i - l;
  if (mi == 0){ if (m == 0) u.re = 1.0; return u; }
  if (mi > 0){
    if (m == mi)       u.re = ((mi & 1) ? -1.0 : 1.0) * s;
    else if (m == -mi) u.re = s;
    return u;
  }
  int mp = -mi;
  if (m == mi)      u.im = s;                            // column -mp
  else if (m == mp) u.im = -((mp & 1) ? -1.0 : 1.0) * s; // column +mp
  return u;
}

constexpr int deg_c(int A){ return (A==0) ? 0 : (A<4 ? 1 : 2); }

constexpr double real_cg_c(int A, int B, int C){
  int l1 = deg_c(A), i = A - l1*l1;
  int l2 = deg_c(B), j = B - l2*l2;
  int l3 = deg_c(C), k = C - l3*l3;
  if (l3 < iabs_c(l1-l2) || l3 > l1+l2) return 0.0;
  int mi = i - l1, mj = j - l2;
  int alist[2] = {mi, -mi}; int na = (mi == 0) ? 1 : 2;
  int blist[2] = {mj, -mj}; int nb = (mj == 0) ? 1 : 2;
  double tr = 0.0, ti = 0.0;
  for (int ai = 0; ai < na; ++ai){
    for (int bi = 0; bi < nb; ++bi){
      int a = alist[ai], b = blist[bi], c = a + b;
      if (iabs_c(c) > l3) continue;
      UC u3 = u_ent_c(l3, k, c);
      if (u3.re == 0.0 && u3.im == 0.0) continue;
      double cgv = cg_cplx_c(l1, a, l2, b, l3, c);
      if (cgv == 0.0) continue;
      UC u1 = u_ent_c(l1, i, a);
      UC u2 = u_ent_c(l2, j, b);
      double pr = u1.re*u2.re - u1.im*u2.im;
      double pi = u1.re*u2.im + u1.im*u2.re;
      double qr = pr*u3.re + pi*u3.im;   // * conj(u3)
      double qi = pi*u3.re - pr*u3.im;
      tr += qr * cgv; ti += qi * cgv;
    }
  }
  return (((l1+l2+l3) & 1) == 0) ? tr : ti;
}

struct CgTab { float v[729]; };
constexpr CgTab make_cg_tab(){
  CgTab t{};
  for (int A = 0; A < 9; ++A)
    for (int B = 0; B < 9; ++B)
      for (int C = 0; C < 9; ++C)
        t.v[(A*9 + B)*9 + C] = (float)real_cg_c(A, B, C);
  return t;
}
__device__ const CgTab CG_TAB = make_cg_tab();   // static init, lives in .data

// trivial device-side copy: .data symbol -> d_ws (graph-safe, ~2 us)
__global__ void copy_cg(float* __restrict__ ws_f){
  int t = blockIdx.x * blockDim.x + threadIdx.x;
  if (t < 729) ws_f[t] = CG_TAB.v[t];
}

// ================= main tensor-product kernel =================
// R9's proven per-n body and launch shape (one-shot 4096 blocks — R10's
// grid-stride regressed). New in R11: the K tensor (54 ch x 512B = 27KB) is
// staged in LDS once per block; do_path reads kv via ds_read_b128
// (conflict-free, ~12cy) instead of 15 global loads per thread.

__device__ __forceinline__ void fma4s(f4& s, float v, const f4& a, const f4& b){
  s += v * a * b;
}

template<int l1,int l2,int l3,int r>
__device__ __forceinline__ void do_path(const float* __restrict__ cg,
    const f4* Klds, int fi,
    const f4* xv, const f4* yv, f4* acc){
  f4 S[2*l3+1];
  #pragma unroll
  for (int k = 0; k < 2*l3+1; ++k) S[k] = (f4)0.f;
  #pragma unroll
  for (int i = 0; i < 2*l1+1; ++i){
    #pragma unroll
    for (int j = 0; j < 2*l2+1; ++j){
      const int m1 = i - l1, m2 = j - l2;
      const int mu1 = m1 < 0 ? -m1 : m1;
      const int mu2 = m2 < 0 ? -m2 : m2;
      const int s1 = (m1 < 0) ? 1 : 0, s2 = (m2 < 0) ? 1 : 0;
      const int s3 = (((l1+l2+l3) & 1) ? 1 : 0) ^ s1 ^ s2;
      #pragma unroll
      for (int t = 0; t < 2; ++t){
        const int lo  = (mu1 > mu2) ? (mu1 - mu2) : (mu2 - mu1);
        const int mu3 = t ? lo : (mu1 + mu2);
        if (t && lo == mu1 + mu2) continue;   // dedupe when a mu is 0
        if (mu3 > l3) continue;
        if (s3 && mu3 == 0) continue;         // no sin-type m3=0 row
        const int k = (s3 ? -mu3 : mu3) + l3;
        const int A = l1*l1 + i, B = l2*l2 + j, C = l3*l3 + k;
        const float v = cg[A*81 + B*9 + C];
        fma4s(S[k], v, xv[A], yv[B]);
      }
    }
  }
  const int koff = ((l1*3 + l2)*2 + r)*3 + l3;
  const f4 kv = Klds[koff*NF4 + fi];
  #pragma unroll
  for (int k = 0; k < 2*l3+1; ++k) acc[k] += kv * S[k];
}

__global__ __launch_bounds__(256) void tp_main(
    const float* __restrict__ xg, const float* __restrict__ yg,
    const float* __restrict__ Kg, float* __restrict__ outg,
    const float* __restrict__ cg){
  __shared__ f4 Klds[54 * NF4];        // full (3,3,2,3,128) kernel tensor, 27KB

  const int tid = threadIdx.x;
  const int fi  = tid & 31;            // float4 lane within feature dim
  const int n   = blockIdx.x * 8 + (tid >> 5);

  // cooperative K stage: 1728 f4 / 256 threads = 7 iterations, coalesced
  {
    const f4* K4 = (const f4*)Kg;
    #pragma unroll
    for (int t = tid; t < 54 * NF4; t += 256) Klds[t] = K4[t];
  }

  const f4* x4 = (const f4*)xg + (size_t)n * 9 * NF4 + fi;
  const f4* y4 = (const f4*)yg + (size_t)n * 9 * NF4 + fi;
  f4* out4 = (f4*)outg + (size_t)n * 18 * NF4 + fi;

  f4 xv[9], yv[9];
  #pragma unroll
  for (int a = 0; a < 9; ++a){
    xv[a] = __builtin_nontemporal_load(&x4[a*NF4]);
    yv[a] = __builtin_nontemporal_load(&y4[a*NF4]);
  }

  __syncthreads();                     // K staged before use

  f4 acc[5];
  const f4 z4 = (f4)0.f;

  // ---- group (r=0, l3=0): paths (0,0),(1,1),(2,2) -> channel 0
  acc[0] = z4;
  do_path<0,0,0,0>(cg, Klds, fi, xv, yv, acc);
  do_path<1,1,0,0>(cg, Klds, fi, xv, yv, acc);
  do_path<2,2,0,0>(cg, Klds, fi, xv, yv, acc);
  __builtin_nontemporal_store(acc[0], &out4[0*NF4]);

  // ---- group (r=0, l3=1): paths (1,1),(2,2) -> channels 1..3
  #pragma unroll
  for (int k = 0; k < 3; ++k) acc[k] = z4;
  do_path<1,1,1,0>(cg, Klds, fi, xv, yv, acc);
  do_path<2,2,1,0>(cg, Klds, fi, xv, yv, acc);
  #pragma unroll
  for (int k = 0; k < 3; ++k) __builtin_nontemporal_store(acc[k], &out4[(1+k)*NF4]);

  // ---- group (r=0, l3=2): paths (1,1),(2,2),(0,2),(2,0) -> channels 4..8
  #pragma unroll
  for (int k = 0; k < 5; ++k) acc[k] = z4;
  do_path<1,1,2,0>(cg, Klds, fi, xv, yv, acc);
  do_path<2,2,2,0>(cg, Klds, fi, xv, yv, acc);
  do_path<0,2,2,0>(cg, Klds, fi, xv, yv, acc);
  do_path<2,0,2,0>(cg, Klds, fi, xv, yv, acc);
  #pragma unroll
  for (int k = 0; k < 5; ++k) __builtin_nontemporal_store(acc[k], &out4[(4+k)*NF4]);

  // ---- group (r=1, l3=0): no parity-allowed paths -> channel 9 is zero
  __builtin_nontemporal_store(z4, &out4[9*NF4]);

  // ---- group (r=1, l3=1): paths (0,1),(1,0),(1,2),(2,1) -> channels 10..12
  #pragma unroll
  for (int k = 0; k < 3; ++k) acc[k] = z4;
  do_path<0,1,1,1>(cg, Klds, fi, xv, yv, acc);
  do_path<1,0,1,1>(cg, Klds, fi, xv, yv, acc);
  do_path<1,2,1,1>(cg, Klds, fi, xv, yv, acc);
  do_path<2,1,1,1>(cg, Klds, fi, xv, yv, acc);
  #pragma unroll
  for (int k = 0; k < 3; ++k) __builtin_nontemporal_store(acc[k], &out4[(10+k)*NF4]);

  // ---- group (r=1, l3=2): paths (1,2),(2,1) -> channels 13..17
  #pragma unroll
  for (int k = 0; k < 5; ++k) acc[k] = z4;
  do_path<1,2,2,1>(cg, Klds, fi, xv, yv, acc);
  do_path<2,1,2,1>(cg, Klds, fi, xv, yv, acc);
  #pragma unroll
  for (int k = 0; k < 5; ++k) __builtin_nontemporal_store(acc[k], &out4[(13+k)*NF4]);
}

extern "C" void kernel_launch(void* const* d_in, const int* in_sizes, int n_in,
                              void* d_out, int out_size, void* d_ws, size_t ws_size,
                              hipStream_t stream){
  const float* x = (const float*)d_in[0];   // (32768, 1, 9, 128)
  const float* y = (const float*)d_in[1];   // (32768, 1, 9, 128)
  const float* K = (const float*)d_in[2];   // (1,3,1,3,2,3,128)
  float* out = (float*)d_out;               // (32768, 2, 9, 128)
  float* ws_f = (float*)d_ws;

  hipLaunchKernelGGL(copy_cg, dim3(1), dim3(768), 0, stream, ws_f);
  hipLaunchKernelGGL(tp_main, dim3(32768/8), dim3(256), 0, stream,
                     x, y, K, out, ws_f);
}

// Round 12
// 106.846 us; speedup vs baseline: 1.1834x; 1.0587x over previous
//
#include <hip/hip_runtime.h>

#define NF4 32   // 128 floats = 32 float4 per (n, channel)

typedef float f4 __attribute__((ext_vector_type(4)));  // clang vector: nontemporal-builtin OK

// ================= compile-time real-CG table =================
// Verified algorithm (R2-R5), evaluated at compile time into a static
// __device__ table; copy_cg moves it to d_ws; tp_main reads it via a
// __restrict__ kernel-arg pointer (the only provenance that preserves the
// fast codegen — R6 literals / R7 laundered pointer spilled, R8 symbol
// lookup aborted the harness).

constexpr double cfact(int n){ double r = 1.0; for (int i = 2; i <= n; ++i) r *= (double)i; return r; }
constexpr int imax2(int a, int b){ return a > b ? a : b; }
constexpr int imin2(int a, int b){ return a < b ? a : b; }
constexpr int iabs_c(int a){ return a < 0 ? -a : a; }
constexpr double csqrt_c(double x){
  double g = x > 1.0 ? x : 1.0;
  for (int i = 0; i < 20; ++i) g = 0.5 * (g + x / g);   // Newton, quadratic -> ulp
  return g;
}

constexpr double cg_cplx_c(int l1,int m1,int l2,int m2,int l3,int m3){
  if (m1 + m2 != m3) return 0.0;
  if (l3 < iabs_c(l1-l2) || l3 > l1+l2) return 0.0;
  double pref = (double)(2*l3+1) * cfact(l1+l2-l3)*cfact(l1-l2+l3)*cfact(-l1+l2+l3)
                / cfact(l1+l2+l3+1);
  pref *= cfact(l3+m3)*cfact(l3-m3)*cfact(l1-m1)*cfact(l1+m1)*cfact(l2-m2)*cfact(l2+m2);
  double s = 0.0;
  int k0 = imax2(0, imax2(l2-l3-m1, l1-l3+m2));
  int k1 = imin2(l1+l2-l3, imin2(l1-m1, l2+m2));
  for (int k = k0; k <= k1; ++k){
    double d = cfact(k)*cfact(l1+l2-l3-k)*cfact(l1-m1-k)*cfact(l2+m2-k)
               *cfact(l3-l2+m1+k)*cfact(l3-l1-m2+k);
    s += ((k & 1) ? -1.0 : 1.0) / d;
  }
  return csqrt_c(pref) * s;
}

struct UC { double re; double im; };
constexpr UC u_ent_c(int l, int i, int m){
  UC u{0.0, 0.0};
  const double s = 0.70710678118654752440;
  int mi = i - l;
  if (mi == 0){ if (m == 0) u.re = 1.0; return u; }
  if (mi > 0){
    if (m == mi)       u.re = ((mi & 1) ? -1.0 : 1.0) * s;
    else if (m == -mi) u.re = s;
    return u;
  }
  int mp = -mi;
  if (m == mi)      u.im = s;                            // column -mp
  else if (m == mp) u.im = -((mp & 1) ? -1.0 : 1.0) * s; // column +mp
  return u;
}

constexpr int deg_c(int A){ return (A==0) ? 0 : (A<4 ? 1 : 2); }

constexpr double real_cg_c(int A, int B, int C){
  int l1 = deg_c(A), i = A - l1*l1;
  int l2 = deg_c(B), j = B - l2*l2;
  int l3 = deg_c(C), k = C - l3*l3;
  if (l3 < iabs_c(l1-l2) || l3 > l1+l2) return 0.0;
  int mi = i - l1, mj = j - l2;
  int alist[2] = {mi, -mi}; int na = (mi == 0) ? 1 : 2;
  int blist[2] = {mj, -mj}; int nb = (mj == 0) ? 1 : 2;
  double tr = 0.0, ti = 0.0;
  for (int ai = 0; ai < na; ++ai){
    for (int bi = 0; bi < nb; ++bi){
      int a = alist[ai], b = blist[bi], c = a + b;
      if (iabs_c(c) > l3) continue;
      UC u3 = u_ent_c(l3, k, c);
      if (u3.re == 0.0 && u3.im == 0.0) continue;
      double cgv = cg_cplx_c(l1, a, l2, b, l3, c);
      if (cgv == 0.0) continue;
      UC u1 = u_ent_c(l1, i, a);
      UC u2 = u_ent_c(l2, j, b);
      double pr = u1.re*u2.re - u1.im*u2.im;
      double pi = u1.re*u2.im + u1.im*u2.re;
      double qr = pr*u3.re + pi*u3.im;   // * conj(u3)
      double qi = pi*u3.re - pr*u3.im;
      tr += qr * cgv; ti += qi * cgv;
    }
  }
  return (((l1+l2+l3) & 1) == 0) ? tr : ti;
}

struct CgTab { float v[729]; };
constexpr CgTab make_cg_tab(){
  CgTab t{};
  for (int A = 0; A < 9; ++A)
    for (int B = 0; B < 9; ++B)
      for (int C = 0; C < 9; ++C)
        t.v[(A*9 + B)*9 + C] = (float)real_cg_c(A, B, C);
  return t;
}
__device__ const CgTab CG_TAB = make_cg_tab();   // static init, lives in .data

// trivial device-side copy: .data symbol -> d_ws (graph-safe, ~2 us)
__global__ void copy_cg(float* __restrict__ ws_f){
  int t = blockIdx.x * blockDim.x + threadIdx.x;
  if (t < 729) ws_f[t] = CG_TAB.v[t];
}

// ================= main tensor-product kernel =================
// R11's proven structure (one-shot 4096 blocks, K tensor in LDS, CG via
// kernel-arg pointer). R12 change: NORMAL stores (L2-writeback buffering,
// like the 7 TB/s fill kernel) instead of nontemporal direct-to-HBM stores;
// loads stay nontemporal (single-use stream, keeps L2 for K).

__device__ __forceinline__ void fma4s(f4& s, float v, const f4& a, const f4& b){
  s += v * a * b;
}

template<int l1,int l2,int l3,int r>
__device__ __forceinline__ void do_path(const float* __restrict__ cg,
    const f4* Klds, int fi,
    const f4* xv, const f4* yv, f4* acc){
  f4 S[2*l3+1];
  #pragma unroll
  for (int k = 0; k < 2*l3+1; ++k) S[k] = (f4)0.f;
  #pragma unroll
  for (int i = 0; i < 2*l1+1; ++i){
    #pragma unroll
    for (int j = 0; j < 2*l2+1; ++j){
      const int m1 = i - l1, m2 = j - l2;
      const int mu1 = m1 < 0 ? -m1 : m1;
      const int mu2 = m2 < 0 ? -m2 : m2;
      const int s1 = (m1 < 0) ? 1 : 0, s2 = (m2 < 0) ? 1 : 0;
      const int s3 = (((l1+l2+l3) & 1) ? 1 : 0) ^ s1 ^ s2;
      #pragma unroll
      for (int t = 0; t < 2; ++t){
        const int lo  = (mu1 > mu2) ? (mu1 - mu2) : (mu2 - mu1);
        const int mu3 = t ? lo : (mu1 + mu2);
        if (t && lo == mu1 + mu2) continue;   // dedupe when a mu is 0
        if (mu3 > l3) continue;
        if (s3 && mu3 == 0) continue;         // no sin-type m3=0 row
        const int k = (s3 ? -mu3 : mu3) + l3;
        const int A = l1*l1 + i, B = l2*l2 + j, C = l3*l3 + k;
        const float v = cg[A*81 + B*9 + C];
        fma4s(S[k], v, xv[A], yv[B]);
      }
    }
  }
  const int koff = ((l1*3 + l2)*2 + r)*3 + l3;
  const f4 kv = Klds[koff*NF4 + fi];
  #pragma unroll
  for (int k = 0; k < 2*l3+1; ++k) acc[k] += kv * S[k];
}

__global__ __launch_bounds__(256) void tp_main(
    const float* __restrict__ xg, const float* __restrict__ yg,
    const float* __restrict__ Kg, float* __restrict__ outg,
    const float* __restrict__ cg){
  __shared__ f4 Klds[54 * NF4];        // full (3,3,2,3,128) kernel tensor, 27KB

  const int tid = threadIdx.x;
  const int fi  = tid & 31;            // float4 lane within feature dim
  const int n   = blockIdx.x * 8 + (tid >> 5);

  // cooperative K stage: 1728 f4 / 256 threads = 7 iterations, coalesced
  {
    const f4* K4 = (const f4*)Kg;
    #pragma unroll
    for (int t = tid; t < 54 * NF4; t += 256) Klds[t] = K4[t];
  }

  const f4* x4 = (const f4*)xg + (size_t)n * 9 * NF4 + fi;
  const f4* y4 = (const f4*)yg + (size_t)n * 9 * NF4 + fi;
  f4* out4 = (f4*)outg + (size_t)n * 18 * NF4 + fi;

  f4 xv[9], yv[9];
  #pragma unroll
  for (int a = 0; a < 9; ++a){
    xv[a] = __builtin_nontemporal_load(&x4[a*NF4]);
    yv[a] = __builtin_nontemporal_load(&y4[a*NF4]);
  }

  __syncthreads();                     // K staged before use

  f4 acc[5];
  const f4 z4 = (f4)0.f;

  // ---- group (r=0, l3=0): paths (0,0),(1,1),(2,2) -> channel 0
  acc[0] = z4;
  do_path<0,0,0,0>(cg, Klds, fi, xv, yv, acc);
  do_path<1,1,0,0>(cg, Klds, fi, xv, yv, acc);
  do_path<2,2,0,0>(cg, Klds, fi, xv, yv, acc);
  out4[0*NF4] = acc[0];

  // ---- group (r=0, l3=1): paths (1,1),(2,2) -> channels 1..3
  #pragma unroll
  for (int k = 0; k < 3; ++k) acc[k] = z4;
  do_path<1,1,1,0>(cg, Klds, fi, xv, yv, acc);
  do_path<2,2,1,0>(cg, Klds, fi, xv, yv, acc);
  #pragma unroll
  for (int k = 0; k < 3; ++k) out4[(1+k)*NF4] = acc[k];

  // ---- group (r=0, l3=2): paths (1,1),(2,2),(0,2),(2,0) -> channels 4..8
  #pragma unroll
  for (int k = 0; k < 5; ++k) acc[k] = z4;
  do_path<1,1,2,0>(cg, Klds, fi, xv, yv, acc);
  do_path<2,2,2,0>(cg, Klds, fi, xv, yv, acc);
  do_path<0,2,2,0>(cg, Klds, fi, xv, yv, acc);
  do_path<2,0,2,0>(cg, Klds, fi, xv, yv, acc);
  #pragma unroll
  for (int k = 0; k < 5; ++k) out4[(4+k)*NF4] = acc[k];

  // ---- group (r=1, l3=0): no parity-allowed paths -> channel 9 is zero
  out4[9*NF4] = z4;

  // ---- group (r=1, l3=1): paths (0,1),(1,0),(1,2),(2,1) -> channels 10..12
  #pragma unroll
  for (int k = 0; k < 3; ++k) acc[k] = z4;
  do_path<0,1,1,1>(cg, Klds, fi, xv, yv, acc);
  do_path<1,0,1,1>(cg, Klds, fi, xv, yv, acc);
  do_path<1,2,1,1>(cg, Klds, fi, xv, yv, acc);
  do_path<2,1,1,1>(cg, Klds, fi, xv, yv, acc);
  #pragma unroll
  for (int k = 0; k < 3; ++k) out4[(10+k)*NF4] = acc[k];

  // ---- group (r=1, l3=2): paths (1,2),(2,1) -> channels 13..17
  #pragma unroll
  for (int k = 0; k < 5; ++k) acc[k] = z4;
  do_path<1,2,2,1>(cg, Klds, fi, xv, yv, acc);
  do_path<2,1,2,1>(cg, Klds, fi, xv, yv, acc);
  #pragma unroll
  for (int k = 0; k < 5; ++k) out4[(13+k)*NF4] = acc[k];
}

extern "C" void kernel_launch(void* const* d_in, const int* in_sizes, int n_in,
                              void* d_out, int out_size, void* d_ws, size_t ws_size,
                              hipStream_t stream){
  const float* x = (const float*)d_in[0];   // (32768, 1, 9, 128)
  const float* y = (const float*)d_in[1];   // (32768, 1, 9, 128)
  const float* K = (const float*)d_in[2];   // (1,3,1,3,2,3,128)
  float* out = (float*)d_out;               // (32768, 2, 9, 128)
  float* ws_f = (float*)d_ws;

  hipLaunchKernelGGL(copy_cg, dim3(1), dim3(768), 0, stream, ws_f);
  hipLaunchKernelGGL(tp_main, dim3(32768/8), dim3(256), 0, stream,
                     x, y, K, out, ws_f);
}